// Round 2
// baseline (266.127 us; speedup 1.0000x reference)
//
#include <hip/hip_runtime.h>
#include <hip/hip_bf16.h>

typedef _Float16 f16x8 __attribute__((ext_vector_type(8)));
typedef float    f32x4 __attribute__((ext_vector_type(4)));

#define NPROTO 1024
#define EMB    512
#define NB     16
#define HW     4096           // 64*64
#define NPIX   (NB * HW)      // 65536
#define INV_TEMP 10.0f        // 1/0.1

// ---------------- prep: prototypes f32 -> fp16, pnorm = |p|^2 (exact f32) ----------------
__global__ void prep_protos(const float* __restrict__ proto,
                            _Float16* __restrict__ Ph,
                            float* __restrict__ pnorm) {
    int k = blockIdx.x;          // 1024 blocks
    int t = threadIdx.x;         // 64 threads, 1 wave
    const float* src = proto + (size_t)k * EMB + t * 8;
    float4 v0 = ((const float4*)src)[0];
    float4 v1 = ((const float4*)src)[1];
    float sq = v0.x*v0.x + v0.y*v0.y + v0.z*v0.z + v0.w*v0.w
             + v1.x*v1.x + v1.y*v1.y + v1.z*v1.z + v1.w*v1.w;
    f16x8 h;
    h[0] = (_Float16)v0.x; h[1] = (_Float16)v0.y; h[2] = (_Float16)v0.z; h[3] = (_Float16)v0.w;
    h[4] = (_Float16)v1.x; h[5] = (_Float16)v1.y; h[6] = (_Float16)v1.z; h[7] = (_Float16)v1.w;
    *(f16x8*)(Ph + (size_t)k * EMB + t * 8) = h;
#pragma unroll
    for (int m = 1; m < 64; m <<= 1) sq += __shfl_xor(sq, m);
    if (t == 0) pnorm[k] = sq;
}

__global__ void zero_counts(int* __restrict__ counts) {
    int i = blockIdx.x * blockDim.x + threadIdx.x;
    if (i < NB * NPROTO) counts[i] = 0;
}

// ---------------- main: GEMM (P * X^T) + dist + softmax + transposed write + argmax ----------------
// Block: 32 contiguous pixels of one image x all 1024 prototypes. 512 thr = 8 waves,
// wave w owns protos [w*128, w*128+128). Acc per wave: 8 Mfrags x 2 Nfrags of f32x4.
__global__ __launch_bounds__(512, 1)
void assign_main(const float* __restrict__ fm, const _Float16* __restrict__ Ph,
                 const float* __restrict__ pnorm, int* __restrict__ counts,
                 float* __restrict__ out) {
    // A tile: [1024 protos][32 c] fp16, row = 64B, XOR-swizzled 16B slots (4-way instead of 8-way conflict)
    __shared__ __align__(16) unsigned char Ald[NPROTO * 64];  // 64 KB
    __shared__ __align__(16) unsigned char Bld[32 * 64];      // 2 KB: [32 px][32 c] fp16, same swizzle
    __shared__ float pn_lds[NPROTO];                          // 4 KB
    __shared__ float xnsum[16 * 32];                          // 2 KB
    __shared__ float xn[32];
    __shared__ float redmax[256];                             // [8 waves][32 px]
    __shared__ float redsum[256];
    __shared__ float argv_[256];
    __shared__ int   argk_[256];

    const int t    = threadIdx.x;
    const int lane = t & 63, wid = t >> 6;
    const int lrow = lane >> 4;      // 0..3  (k-group for frags / row-group for D)
    const int lcol = lane & 15;      // row (A) / col=pixel (B, D)

    const int n0  = blockIdx.x * 32;     // first global pixel
    const int b   = n0 >> 12;            // 4096 px per image
    const int hw0 = n0 & 4095;

    pn_lds[t]       = pnorm[t];
    pn_lds[t + 512] = pnorm[t + 512];

    f32x4 acc[8][2];
#pragma unroll
    for (int i = 0; i < 8; ++i)
#pragma unroll
        for (int j = 0; j < 2; ++j)
#pragma unroll
            for (int e = 0; e < 4; ++e) acc[i][j][e] = 0.0f;

    float sq = 0.0f;                 // per-thread partial of |x|^2 (exact f32)
    const int bpx = t & 31;          // staging pixel
    const int bcg = t >> 5;          // staging channel sub (0..15)
    const float* fmB = fm + (size_t)b * EMB * HW + hw0;

    for (int ks = 0; ks < 16; ++ks) {
        const int c0 = ks * 32;
        // stage A (prototypes): 1024 x 32 fp16, 8 passes of 512 x 16B
#pragma unroll
        for (int p = 0; p < 8; ++p) {
            int k  = p * 128 + (t >> 2);
            int cg = t & 3;
            uint4 v = *(const uint4*)(Ph + (size_t)k * EMB + c0 + cg * 8);
            int off = k * 64 + ((cg * 16) ^ ((k & 3) << 4));
            *(uint4*)(Ald + off) = v;
        }
        // stage B (pixels, f32->fp16) + accumulate |x|^2 in f32
#pragma unroll
        for (int p = 0; p < 2; ++p) {
            int c = bcg + p * 16;
            float v = fmB[(size_t)(c0 + c) * HW + bpx];
            sq += v * v;
            int off = bpx * 64 + ((c * 2) ^ ((bpx & 3) << 4));
            *(_Float16*)(Bld + off) = (_Float16)v;
        }
        __syncthreads();

        f16x8 bf[2];
#pragma unroll
        for (int nf = 0; nf < 2; ++nf) {
            int px  = nf * 16 + lcol;
            int off = px * 64 + ((lrow * 16) ^ ((px & 3) << 4));
            bf[nf] = *(const f16x8*)(Bld + off);
        }
#pragma unroll
        for (int mf = 0; mf < 8; ++mf) {
            int r   = wid * 128 + mf * 16 + lcol;
            int off = r * 64 + ((lrow * 16) ^ ((r & 3) << 4));
            f16x8 af = *(const f16x8*)(Ald + off);
            acc[mf][0] = __builtin_amdgcn_mfma_f32_16x16x32_f16(af, bf[0], acc[mf][0], 0, 0, 0);
            acc[mf][1] = __builtin_amdgcn_mfma_f32_16x16x32_f16(af, bf[1], acc[mf][1], 0, 0, 0);
        }
        __syncthreads();
    }

    // ---- xnorm: reduce 16 partials per pixel ----
    xnsum[bcg * 32 + bpx] = sq;
    __syncthreads();
    if (t < 32) {
        float s = 0.0f;
#pragma unroll
        for (int g = 0; g < 16; ++g) s += xnsum[g * 32 + t];
        xn[t] = s;
    }
    __syncthreads();

    // ---- logits = -10 * sqrt(max(|x|^2 + |p|^2 - 2 x.p, 0)); track max & argmax ----
    float lmax[2] = {-1e30f, -1e30f};
    float lav[2]  = {-1e30f, -1e30f};
    int   lak[2]  = {0, 0};
#pragma unroll
    for (int mf = 0; mf < 8; ++mf) {
#pragma unroll
        for (int nf = 0; nf < 2; ++nf) {
            int px = nf * 16 + lcol;
#pragma unroll
            for (int j = 0; j < 4; ++j) {
                int kidx = wid * 128 + mf * 16 + lrow * 4 + j;   // D row (verified m89 mapping)
                float d2 = xn[px] + pn_lds[kidx] - 2.0f * acc[mf][nf][j];
                float lg = -INV_TEMP * sqrtf(fmaxf(d2, 0.0f));
                acc[mf][nf][j] = lg;
                if (lg > lav[nf]) { lav[nf] = lg; lak[nf] = kidx; }  // ascending k => first-index tie-break
                lmax[nf] = fmaxf(lmax[nf], lg);
            }
        }
    }
    // reduce across the 4 lane-groups sharing a pixel column (xor 16, 32)
#pragma unroll
    for (int nf = 0; nf < 2; ++nf) {
#pragma unroll
        for (int m = 16; m <= 32; m <<= 1) {
            float ov = __shfl_xor(lav[nf], m);
            int   ok = __shfl_xor(lak[nf], m);
            if (ov > lav[nf] || (ov == lav[nf] && ok < lak[nf])) { lav[nf] = ov; lak[nf] = ok; }
            lmax[nf] = fmaxf(lmax[nf], __shfl_xor(lmax[nf], m));
        }
    }
    if (lane < 16) {
#pragma unroll
        for (int nf = 0; nf < 2; ++nf) {
            int idx = wid * 32 + nf * 16 + lane;
            redmax[idx] = lmax[nf];
            argv_[idx]  = lav[nf];
            argk_[idx]  = lak[nf];
        }
    }
    __syncthreads();

    // ---- global (all 1024 protos) max / argmax per pixel; exp + partial sums ----
    float gmax[2];
#pragma unroll
    for (int nf = 0; nf < 2; ++nf) {
        int col = nf * 16 + lcol;
        float gm = -1e30f, gav = -1e30f;
        int gak = 0;
#pragma unroll
        for (int w = 0; w < 8; ++w) {           // ascending wave = ascending k
            gm = fmaxf(gm, redmax[w * 32 + col]);
            float av = argv_[w * 32 + col];
            int   ak = argk_[w * 32 + col];
            if (av > gav || (av == gav && ak < gak)) { gav = av; gak = ak; }
        }
        gmax[nf] = gm;
        if (wid == 0 && lrow == 0) atomicAdd(&counts[b * NPROTO + gak], 1);

        float s = 0.0f;
#pragma unroll
        for (int mf = 0; mf < 8; ++mf)
#pragma unroll
            for (int j = 0; j < 4; ++j) {
                float e = expf(acc[mf][nf][j] - gm);
                acc[mf][nf][j] = e;
                s += e;
            }
        s += __shfl_xor(s, 16);
        s += __shfl_xor(s, 32);
        if (lane < 16) redsum[wid * 32 + nf * 16 + lane] = s;
    }
    __syncthreads();

    // ---- normalize and write transposed output: out[b][k][hw0+px], 16-lane 64B segments ----
    const size_t obase = (size_t)b * NPROTO * HW + hw0;
#pragma unroll
    for (int nf = 0; nf < 2; ++nf) {
        int col = nf * 16 + lcol;
        float s = 0.0f;
#pragma unroll
        for (int w = 0; w < 8; ++w) s += redsum[w * 32 + col];
        float inv = 1.0f / s;
#pragma unroll
        for (int mf = 0; mf < 8; ++mf)
#pragma unroll
            for (int j = 0; j < 4; ++j) {
                int kidx = wid * 128 + mf * 16 + lrow * 4 + j;
                out[obase + (size_t)kidx * HW + col] = acc[mf][nf][j] * inv;
            }
    }
}

// ---------------- finalize: mask = (counts > 3).sum() / 16 ----------------
__global__ void finalize(const int* __restrict__ counts, float* __restrict__ out) {
    int t = threadIdx.x;  // 256
    int local = 0;
    for (int i = t; i < NB * NPROTO; i += 256) local += (counts[i] > 3) ? 1 : 0;
#pragma unroll
    for (int m = 1; m < 64; m <<= 1) local += __shfl_xor(local, m);
    __shared__ int wsum[4];
    if ((t & 63) == 0) wsum[t >> 6] = local;
    __syncthreads();
    if (t == 0) out[(size_t)NPIX * NPROTO] = (float)(wsum[0] + wsum[1] + wsum[2] + wsum[3]) / 16.0f;
}

extern "C" void kernel_launch(void* const* d_in, const int* in_sizes, int n_in,
                              void* d_out, int out_size, void* d_ws, size_t ws_size,
                              hipStream_t stream) {
    const float* fm    = (const float*)d_in[0];   // [16][512][64][64] f32
    const float* proto = (const float*)d_in[1];   // [1][1024][512] f32
    float* out = (float*)d_out;                   // sims (67108864) + mask (1)

    char* ws = (char*)d_ws;
    _Float16* Ph   = (_Float16*)ws;                                    // 1 MB
    float*    pnorm = (float*)(ws + (size_t)NPROTO * EMB * 2);         // 4 KB
    int*      counts = (int*)(ws + (size_t)NPROTO * EMB * 2 + 4096);   // 64 KB

    prep_protos<<<NPROTO, 64, 0, stream>>>(proto, Ph, pnorm);
    zero_counts<<<(NB * NPROTO + 255) / 256, 256, 0, stream>>>(counts);
    assign_main<<<NPIX / 32, 512, 0, stream>>>(fm, Ph, pnorm, counts, out);
    finalize<<<1, 256, 0, stream>>>(counts, out);
}